// Round 1
// 250.825 us; speedup vs baseline: 1.0524x; 1.0524x over previous
//
#include <hip/hip_runtime.h>
#include <hip/hip_bf16.h>
#include <math.h>

// MoLE layer: out = gelu(x @ base_w^T + base_b) + top1_w * (gelu(x @ A[e]) @ B[e])
// probs = softmax(x @ gate_w^T + gate_b)
// T=8192 tokens, D=2048, E=8 experts, RANK=16.
//
// Pipeline (3 kernels):
//  k1 cvt_logits: token blocks (8 tokens each) convert x fp32->bf16 AND compute
//     fp32 logits/softmax/argmax with gate_w cached in REGISTERS; other blocks
//     convert base_w and do LDS-tiled transposes lora_B -> Bt, lora_A -> Ab.
//  k2 hsel: dense H = Xb @ Ab over ALL experts (K=2048), 32x64 tiles, grid
//     (256,2); epilogue writes one-hot A2[t][e*16+r] = (idx==e)*w*gelu(H).
//  k3 gemm: 256x256 tile, 512 threads (8 waves, 2Mx4N), BK=32 with a 4-deep
//     LDS ring (128 KiB). Counted-vmcnt pipeline (T3+T4): staging runs 3
//     K-tiles ahead, per-K-tile wait is vmcnt(8) (never 0 in main loop).
//     Two 16-MFMA phases per K-tile with raw s_barrier + setprio(1) around the
//     MFMA cluster (T5). XOR-swizzled LDS (chunk ^ ((row>>1)&3)), proven
//     conflict-free in hsel. Epilogue: +bias, GELU, LoRA as 4 extra K=32
//     MFMAs from A2/Bt, store fp32.

#define DIM   2048
#define RANK  16
#define NEXP  8
#define NTOK  8192
#define KLORA 128   // NEXP*RANK

// gemm geometry
#define BM   256
#define BN   256
#define BK   32
#define NBUF 4
#define NKT  (DIM / BK)   // 64

typedef __hip_bfloat16 bf16;
typedef __attribute__((ext_vector_type(8))) short short8;  // 8 bf16 = 4 VGPRs
typedef __attribute__((ext_vector_type(4))) float float4v;

typedef const __attribute__((address_space(1))) void* gptr_t;
typedef __attribute__((address_space(3))) void*       sptr_t;

__device__ __forceinline__ void async_ld16(const bf16* g, bf16* l) {
    __builtin_amdgcn_global_load_lds((gptr_t)g, (sptr_t)l, 16, 0, 0);
}

// tanh-approx GELU: |err vs erf-gelu| <= ~3e-3, well under 0.1 threshold
__device__ __forceinline__ float gelu_fast(float x) {
    float t = 0.7978845608028654f * (x + 0.044715f * x * x * x);
    t = fminf(fmaxf(t, -10.0f), 10.0f);
    float e = __expf(2.0f * t);
    float th = (e - 1.0f) / (e + 1.0f);
    return 0.5f * x * (1.0f + th);
}

__device__ __forceinline__ short8 pack8(float4 v0, float4 v1) {
    union { bf16 h[8]; short8 v; } u;
    u.h[0] = __float2bfloat16(v0.x); u.h[1] = __float2bfloat16(v0.y);
    u.h[2] = __float2bfloat16(v0.z); u.h[3] = __float2bfloat16(v0.w);
    u.h[4] = __float2bfloat16(v1.x); u.h[5] = __float2bfloat16(v1.y);
    u.h[6] = __float2bfloat16(v1.z); u.h[7] = __float2bfloat16(v1.w);
    return u.v;
}

// --------------------------------------------------------- cvt+logits kernel
// blocks [0,1024): 8 tokens each, cvt + fp32 logits (gate_w in registers).
// [1024,3072): base_w cvt.  [3072,3328): Bt transpose.  [3328,3456): Ab transp.
__global__ __launch_bounds__(256) void cvt_logits_kernel(
    const float* __restrict__ x, const float* __restrict__ gate_w,
    const float* __restrict__ gate_b, const float* __restrict__ base_w,
    const float* __restrict__ lora_B, const float* __restrict__ lora_A,
    bf16* __restrict__ Xb, bf16* __restrict__ Wb,
    bf16* __restrict__ Bt, bf16* __restrict__ Ab,
    float* __restrict__ probs, int* __restrict__ idx_out, float* __restrict__ w_out)
{
    __shared__ float buf[2560];         // shared scratch for all branches
    const int b   = blockIdx.x;
    const int tid = threadIdx.x;

    if (b < 1024) {
        // ---- 8 tokens: convert + fp32 logits ----
        const int t0 = b * 8;
        float4 g0[NEXP], g1[NEXP];      // gate_w slice: 8 experts x 8 floats
        #pragma unroll
        for (int e = 0; e < NEXP; e++) {
            const float* wr = gate_w + (size_t)e * DIM + tid * 8;
            g0[e] = *(const float4*)wr;
            g1[e] = *(const float4*)(wr + 4);
        }
        const int wave = tid >> 6, lane = tid & 63;
        #pragma unroll
        for (int tt = 0; tt < 8; tt++) {
            const int t = t0 + tt;
            const float* xr = x + (size_t)t * DIM + tid * 8;
            float4 v0 = *(const float4*)xr;
            float4 v1 = *(const float4*)(xr + 4);
            *(short8*)(Xb + (size_t)t * DIM + tid * 8) = pack8(v0, v1);
            float a[NEXP];
            #pragma unroll
            for (int e = 0; e < NEXP; e++) {
                a[e] = v0.x * g0[e].x + v0.y * g0[e].y + v0.z * g0[e].z + v0.w * g0[e].w
                     + v1.x * g1[e].x + v1.y * g1[e].y + v1.z * g1[e].z + v1.w * g1[e].w;
                #pragma unroll
                for (int off = 32; off > 0; off >>= 1) a[e] += __shfl_down(a[e], off);
            }
            if (lane == 0) {
                #pragma unroll
                for (int e = 0; e < NEXP; e++) buf[tt * 32 + wave * NEXP + e] = a[e];
            }
        }
        __syncthreads();
        if (tid < 8) {                  // thread tid finalizes token t0+tid
            const int t = t0 + tid;
            float l[NEXP]; float mx = -1e30f;
            #pragma unroll
            for (int e = 0; e < NEXP; e++) {
                l[e] = buf[tid * 32 + e] + buf[tid * 32 + 8 + e]
                     + buf[tid * 32 + 16 + e] + buf[tid * 32 + 24 + e] + gate_b[e];
                mx = fmaxf(mx, l[e]);
            }
            float sum = 0.f;
            #pragma unroll
            for (int e = 0; e < NEXP; e++) { l[e] = __expf(l[e] - mx); sum += l[e]; }
            float inv = 1.0f / sum;
            int es = 0; float best = l[0];
            #pragma unroll
            for (int e = 1; e < NEXP; e++) if (l[e] > best) { best = l[e]; es = e; }
            #pragma unroll
            for (int e = 0; e < NEXP; e++) probs[(size_t)t * NEXP + e] = l[e] * inv;
            idx_out[t] = es;
            w_out[t]   = best * inv;
        }
    } else if (b < 1024 + 2048) {
        // ---- base_w convert: 8 floats/thread ----
        size_t v = ((size_t)(b - 1024) * 256 + tid) * 8;
        float4 v0 = *(const float4*)(base_w + v);
        float4 v1 = *(const float4*)(base_w + v + 4);
        *(short8*)(Wb + v) = pack8(v0, v1);
    } else if (b < 1024 + 2048 + 256) {
        // ---- Bt transpose: lora_B [128][2048] -> Bt [2048][128], 32x32 tile
        int bb = b - 1024 - 2048;
        int kk0 = (bb >> 6) * 32, j0 = (bb & 63) * 32;
        {   // read coalesced along j
            int r = tid >> 3, c4 = (tid & 7) * 4;
            float4 val = *(const float4*)(lora_B + (size_t)(kk0 + r) * DIM + j0 + c4);
            *(float4*)(buf + r * 36 + c4) = val;
        }
        __syncthreads();
        {   // write coalesced along kk
            int j = tid >> 3, k4 = (tid & 7) * 4;
            bf16* dst = Bt + (size_t)(j0 + j) * KLORA + kk0 + k4;
            #pragma unroll
            for (int i = 0; i < 4; i++) dst[i] = __float2bfloat16(buf[(k4 + i) * 36 + j]);
        }
    } else {
        // ---- Ab transpose: lora_A [8][2048][16] -> Ab [128][2048]
        int bb = b - 1024 - 2048 - 256;
        int e = bb >> 4, k0 = (bb & 15) * 128;
        const float* src = lora_A + (size_t)e * DIM * RANK;
        {
            int k = tid >> 2, r4 = (tid & 3) * 4;
            float4 va = *(const float4*)(src + (size_t)(k0 + k) * RANK + r4);
            float4 vb = *(const float4*)(src + (size_t)(k0 + k + 64) * RANK + r4);
            *(float4*)(buf + k * 20 + r4)        = va;
            *(float4*)(buf + (k + 64) * 20 + r4) = vb;
        }
        __syncthreads();
        {
            int r = tid >> 4, kx = (tid & 15) * 8;
            bf16* dst = Ab + (size_t)(e * 16 + r) * DIM + k0 + kx;
            #pragma unroll
            for (int i = 0; i < 8; i++) dst[i] = __float2bfloat16(buf[(kx + i) * 20 + r]);
        }
    }
}

// ---------------------------------------------------------------- hsel kernel
// H = Xb @ Ab (all experts, K=2048), 32x64 tile, grid (256,2) = 512 blocks.
// Epilogue: A2[t][jcol] = (idx[t]==jcol>>4) * w[t] * gelu(H).
__global__ __launch_bounds__(256) void hsel_kernel(
    const bf16* __restrict__ Xb, const bf16* __restrict__ Ab,
    const int* __restrict__ idx, const float* __restrict__ wsel,
    bf16* __restrict__ A2)
{
    __shared__ bf16 As[32 * 32];
    __shared__ bf16 Bs[64 * 32];
    const int tid  = threadIdx.x;
    const int wave = tid >> 6, lane = tid & 63;
    const int m0 = blockIdx.x * 32;
    const int n0 = blockIdx.y * 64;
    const int col = lane & 15, quad = lane >> 4;

    const int kc = ((tid & 3) ^ ((tid >> 3) & 3)) * 8;
    const bf16* gB = Ab + (size_t)(n0 + (tid >> 2)) * DIM + kc;
    const bf16* gA = Xb + (size_t)(m0 + (tid >> 2)) * DIM + kc;   // tid<128 only
    bf16* lB = Bs + wave * 512;
    bf16* lA = As + wave * 512;

    const int xr = quad ^ ((col >> 1) & 3);
    const bf16* pa = As + col * 32 + xr * 8;
    const bf16* pb = Bs + (wave * 16 + col) * 32 + xr * 8;

    float4v acc[2] = {};
    for (int k0 = 0; k0 < DIM; k0 += 32) {
        __syncthreads();
        async_ld16(gB + k0, lB);
        if (tid < 128) async_ld16(gA + k0, lA);
        __syncthreads();
        short8 a0 = *(const short8*)pa;
        short8 a1 = *(const short8*)(pa + 512);
        short8 b0 = *(const short8*)pb;
        acc[0] = __builtin_amdgcn_mfma_f32_16x16x32_bf16(a0, b0, acc[0], 0, 0, 0);
        acc[1] = __builtin_amdgcn_mfma_f32_16x16x32_bf16(a1, b0, acc[1], 0, 0, 0);
    }

    const int jcol = n0 + wave * 16 + col;
    const int ej   = jcol >> 4;
    #pragma unroll
    for (int i = 0; i < 2; i++) {
        int rbase = m0 + i * 16 + quad * 4;
        #pragma unroll
        for (int r = 0; r < 4; r++) {
            int t = rbase + r;
            float v = (idx[t] == ej) ? gelu_fast(acc[i][r]) * wsel[t] : 0.0f;
            A2[(size_t)t * KLORA + jcol] = __float2bfloat16(v);
        }
    }
}

// --------------------------------------------------------------- GEMM kernel
// 256x256 tile, 8 waves (2Mx4N), per-wave 128x64 output. BK=32, 4-buffer LDS
// ring (128 KiB), staging 3 K-tiles ahead, counted vmcnt(8) per K-tile.
// Two phases per K-tile: {8 ds_read_b128 || 2 global_load_lds -> s_barrier ->
// setprio(1) 16 MFMA setprio(0) -> s_barrier}.
__global__ __launch_bounds__(512, 2) void gemm_kernel(
    const bf16* __restrict__ Xb, const bf16* __restrict__ Wb,
    const float* __restrict__ base_b,
    const bf16* __restrict__ A2, const bf16* __restrict__ Bt,
    float* __restrict__ out)
{
    __shared__ bf16 As[NBUF * BM * BK];   // 64 KB
    __shared__ bf16 Bs[NBUF * BN * BK];   // 64 KB
    const int tid  = threadIdx.x;
    const int wave = tid >> 6, lane = tid & 63;
    const int wm = wave >> 2, wn = wave & 3;      // 2 x 4 wave grid
    const int n0 = blockIdx.x * BN;               // n fastest (8 n-tiles)
    const int m0 = blockIdx.y * BM;               // 32 m-tiles
    const int col = lane & 15, quad = lane >> 4;

    // staging: per K-tile each matrix = 2 rounds of 512 threads x 16B.
    // round r, thread tid -> LDS row r*128 + (tid>>2), slot tid&3;
    // global chunk = slot ^ ((row>>1)&3) = (tid&3) ^ ((tid>>3)&3)  (hsel-proven)
    const int kc = ((tid & 3) ^ ((tid >> 3) & 3)) * 8;
    const int sr = tid >> 2;                      // 0..127
    const bf16* gA = Xb + (size_t)(m0 + sr) * DIM + kc;
    const bf16* gB = Wb + (size_t)(n0 + sr) * DIM + kc;
    bf16* lAw = As + wave * 512;                  // wave-uniform LDS dst base
    bf16* lBw = Bs + wave * 512;                  // (+4096 elems for round 1)

    // frag read: row = wm*128 + i*16 + col (A) / wn*64 + j*16 + col (B),
    // slot = quad ^ ((col>>1)&3)  -> 2-way (free) bank pattern
    const int slot = (quad ^ ((col >> 1) & 3)) * 8;
    const int raoff = (wm * 128 + col) * BK + slot;
    const int rboff = (wn * 64  + col) * BK + slot;

    float4v acc[8][4] = {};

    // ---- prologue: stage K-tiles 0,1,2 (12 loads/thread) ----
    #pragma unroll
    for (int t = 0; t < 3; t++) {
        const bf16* ga = gA + t * BK;
        const bf16* gb = gB + t * BK;
        bf16* la = lAw + t * (BM * BK);
        bf16* lb = lBw + t * (BN * BK);
        async_ld16(ga, la);
        async_ld16(gb, lb);
        async_ld16(ga + (size_t)128 * DIM, la + 4096);
        async_ld16(gb + (size_t)128 * DIM, lb + 4096);
    }
    asm volatile("s_waitcnt vmcnt(8)" ::: "memory");   // K-tile 0 resident
    __builtin_amdgcn_sched_barrier(0);
    __builtin_amdgcn_s_barrier();

    #pragma unroll 4
    for (int T = 0; T < NKT; T++) {
        const int bufc = T & 3;
        const bf16* pa = As + bufc * (BM * BK) + raoff;
        const bf16* pb = Bs + bufc * (BN * BK) + rboff;
        const int ts = T + 3, bufs = ts & 3;
        const bool st = (ts < NKT);
        const bf16* gsa = gA + ts * BK;
        const bf16* gsb = gB + ts * BK;
        bf16* lsa = lAw + bufs * (BM * BK);
        bf16* lsb = lBw + bufs * (BN * BK);

        short8 a[4], b[4];
        // ---------------- phase 0: m-frags 0-3, all B frags ----------------
        #pragma unroll
        for (int i = 0; i < 4; i++) a[i] = *(const short8*)(pa + i * 16 * BK);
        #pragma unroll
        for (int j = 0; j < 4; j++) b[j] = *(const short8*)(pb + j * 16 * BK);
        if (st) {                       // stage round 0 of K-tile T+3
            async_ld16(gsa, lsa);
            async_ld16(gsb, lsb);
        }
        __builtin_amdgcn_s_barrier();
        __builtin_amdgcn_s_setprio(1);
        #pragma unroll
        for (int i = 0; i < 4; i++)
            #pragma unroll
            for (int j = 0; j < 4; j++)
                acc[i][j] = __builtin_amdgcn_mfma_f32_16x16x32_bf16(
                    a[i], b[j], acc[i][j], 0, 0, 0);
        __builtin_amdgcn_s_setprio(0);
        __builtin_amdgcn_s_barrier();
        // ---------------- phase 1: m-frags 4-7, reuse b[] ------------------
        #pragma unroll
        for (int i = 0; i < 4; i++) a[i] = *(const short8*)(pa + (i + 4) * 16 * BK);
        if (st) {                       // stage round 1 of K-tile T+3
            async_ld16(gsa + (size_t)128 * DIM, lsa + 4096);
            async_ld16(gsb + (size_t)128 * DIM, lsb + 4096);
        }
        __builtin_amdgcn_s_barrier();
        __builtin_amdgcn_s_setprio(1);
        #pragma unroll
        for (int i = 0; i < 4; i++)
            #pragma unroll
            for (int j = 0; j < 4; j++)
                acc[i + 4][j] = __builtin_amdgcn_mfma_f32_16x16x32_bf16(
                    a[i], b[j], acc[i + 4][j], 0, 0, 0);
        __builtin_amdgcn_s_setprio(0);
        // counted drain: keep 2 K-tiles (8 loads) in flight; decay at tail
        if (T + 3 < NKT)      asm volatile("s_waitcnt vmcnt(8)" ::: "memory");
        else if (T + 3 == NKT) asm volatile("s_waitcnt vmcnt(4)" ::: "memory");
        else                   asm volatile("s_waitcnt vmcnt(0)" ::: "memory");
        __builtin_amdgcn_sched_barrier(0);
        __builtin_amdgcn_s_barrier();
    }

    // epilogue 1: bias + GELU (C/D: row = quad*4+reg, col = lane&15)
    float bias[4];
    #pragma unroll
    for (int j = 0; j < 4; j++) bias[j] = base_b[n0 + wn * 64 + j * 16 + col];
    #pragma unroll
    for (int i = 0; i < 8; i++)
        #pragma unroll
        for (int j = 0; j < 4; j++)
            #pragma unroll
            for (int r = 0; r < 4; r++)
                acc[i][j][r] = gelu_fast(acc[i][j][r] + bias[j]);

    // epilogue 2: LoRA as K=128 MFMA extension (4 steps of K=32)
    const bf16* pea = A2 + (size_t)(m0 + wm * 128 + col) * KLORA + quad * 8;
    const bf16* peb = Bt + (size_t)(n0 + wn * 64  + col) * KLORA + quad * 8;
    #pragma unroll
    for (int ks = 0; ks < 4; ks++) {
        short8 ea[8], eb[4];
        #pragma unroll
        for (int i = 0; i < 8; i++)
            ea[i] = *(const short8*)(pea + i * 16 * KLORA + ks * 32);
        #pragma unroll
        for (int j = 0; j < 4; j++)
            eb[j] = *(const short8*)(peb + j * 16 * KLORA + ks * 32);
        #pragma unroll
        for (int i = 0; i < 8; i++)
            #pragma unroll
            for (int j = 0; j < 4; j++)
                acc[i][j] = __builtin_amdgcn_mfma_f32_16x16x32_bf16(
                    ea[i], eb[j], acc[i][j], 0, 0, 0);
    }

    // store fp32
    #pragma unroll
    for (int i = 0; i < 8; i++) {
        #pragma unroll
        for (int j = 0; j < 4; j++) {
            int tt = m0 + wm * 128 + i * 16 + quad * 4;
            int jj = n0 + wn * 64  + j * 16 + col;
            float* po = out + (size_t)tt * DIM + jj;
            #pragma unroll
            for (int r = 0; r < 4; r++) po[(size_t)r * DIM] = acc[i][j][r];
        }
    }
}

// ------------------------------------------------------------------- launch
extern "C" void kernel_launch(void* const* d_in, const int* in_sizes, int n_in,
                              void* d_out, int out_size, void* d_ws, size_t ws_size,
                              hipStream_t stream)
{
    (void)in_sizes; (void)n_in; (void)out_size; (void)ws_size;
    const float* x      = (const float*)d_in[0];
    const float* gate_w = (const float*)d_in[1];
    const float* gate_b = (const float*)d_in[2];
    const float* base_w = (const float*)d_in[3];
    const float* base_b = (const float*)d_in[4];
    const float* lora_A = (const float*)d_in[5];
    const float* lora_B = (const float*)d_in[6];

    float* out   = (float*)d_out;                    // [8192, 2048]
    float* probs = out + (size_t)NTOK * DIM;         // [8192, 8]

    // workspace layout (~45.2 MB)
    char* ws = (char*)d_ws;
    bf16*  Xb   = (bf16*)ws;                          // 33,554,432 B
    bf16*  Wb   = (bf16*)(ws + 33554432);             //  8,388,608 B
    bf16*  A2   = (bf16*)(ws + 41943040);             //  2,097,152 B
    bf16*  Bt   = (bf16*)(ws + 44040192);             //    524,288 B
    bf16*  Ab   = (bf16*)(ws + 44564480);             //    524,288 B
    int*   idx  = (int*) (ws + 45088768);             //     32,768 B
    float* wsel = (float*)(ws + 45121536);            //     32,768 B

    cvt_logits_kernel<<<1024 + 2048 + 256 + 128, 256, 0, stream>>>(
        x, gate_w, gate_b, base_w, lora_B, lora_A,
        Xb, Wb, Bt, Ab, probs, idx, wsel);
    hsel_kernel<<<dim3(256, 2), 256, 0, stream>>>(Xb, Ab, idx, wsel, A2);
    gemm_kernel<<<dim3(8, 32), 512, 0, stream>>>(Xb, Wb, base_b, A2, Bt, out);
}